// Round 2
// baseline (920.334 us; speedup 1.0000x reference)
//
#include <hip/hip_runtime.h>

typedef unsigned int uint;

#define BATCH 32
#define NCH   256
#define HW    16384

// ---------------------------------------------------------------------------
// Kernel 1: fused spatial pool, single pass over x (512 MiB fp32).
// e_n = exp(<x[:,n],w>+b) accumulated UNNORMALIZED (|logit| <~ 4, exp safe in
// fp32): ctxnum[b,c] = sum_n x[b,c,n]*e_n, zbuf[b] = sum_n e_n via fp32
// atomics; the division happens in the tail kernel.
//
// Grid: 32 b x 64 blocks; each block owns 256 n, processed as 4 chunks of 64.
// Thread (r = tid>>3, m = tid&7) loads an 8c x 8n register slice per chunk
// (c = it*32+r, n = n0+m*8..+7), contributes logit partials from registers,
// then reuses the SAME registers for the context accumulation — x is touched
// exactly once, no LDS data tile.
//
// v2 changes vs previous round:
//  * logit r-reduction in-register: __shfl_xor over lane bits 3..5 sums the
//    8 r-rows per wave; only lanes rl==0 write a 64-float wave partial.
//    Phase B becomes 4 LDS reads + exp (was a 32-iteration serial column
//    walk by one wave while 3 waves idled).
//  * 2 barriers/chunk instead of 3 (trailing barrier proven unnecessary:
//    sync2 separates B's wpart reads from next-A's wpart writes; next sync1
//    separates C's earr reads from next-B's earr writes).
//  * Z reduction deferred out of the chunk loop (once, not 4x).
//  * mask weights hoisted to registers (wc[8]) before the loop.
//  * __launch_bounds__(256,4): pin VGPRs <=128 so 4 blocks/CU are resident
//    and barrier phases of one block overlap memory phases of another.
// ---------------------------------------------------------------------------
__global__ __launch_bounds__(256, 4) void spool_kernel(
    const float* __restrict__ x, const float* __restrict__ mask_w,
    const float* __restrict__ mask_b, float* __restrict__ ctxnum,
    float* __restrict__ zbuf)
{
    __shared__ float wlds[NCH];
    __shared__ float wpart[4][64];    // per-wave logit partials
    __shared__ float earr[64];        // exp(logit) for the chunk

    const int tid  = threadIdx.x;
    const int b    = blockIdx.x >> 6;
    const int blk  = blockIdx.x & 63;
    const int r    = tid >> 3;        // 0..31: c within a 32-row group
    const int m    = tid & 7;         // 0..7 : n-octet
    const int wave = tid >> 6;        // 0..3
    const int rl   = r & 7;           // r within wave (lane bits 3..5)

    wlds[tid] = mask_w[tid];
    const float mb = mask_b[0];
    __syncthreads();

    // Hoist this thread's 8 channel weights (c = it*32 + r) out of the loop.
    float wc[8];
    #pragma unroll
    for (int it = 0; it < 8; ++it) wc[it] = wlds[(it << 5) + r];

    float acc[8] = {0.f,0.f,0.f,0.f,0.f,0.f,0.f,0.f}; // ctx partial per it
    float zacc = 0.f;                                  // live on tid<64

    const float* xb = x + ((size_t)b << 22) + ((size_t)r << 14) + (m << 3);

    for (int g = 0; g < 4; ++g) {
        const int n0 = (blk << 8) + (g << 6);

        // ---- Phase A: global->registers + logit partials (in-register) ----
        float4 d0[8], d1[8];
        float la[8] = {0.f,0.f,0.f,0.f,0.f,0.f,0.f,0.f};
        #pragma unroll
        for (int it = 0; it < 8; ++it) {
            const float4* p = (const float4*)(xb + ((size_t)it << 19) + n0);
            d0[it] = p[0];
            d1[it] = p[1];
            const float w = wc[it];
            la[0] += w * d0[it].x; la[1] += w * d0[it].y;
            la[2] += w * d0[it].z; la[3] += w * d0[it].w;
            la[4] += w * d1[it].x; la[5] += w * d1[it].y;
            la[6] += w * d1[it].z; la[7] += w * d1[it].w;
        }
        // Reduce over the 8 r-rows held by this wave: lane bits 3..5.
        #pragma unroll
        for (int k = 0; k < 8; ++k) {
            float v = la[k];
            v += __shfl_xor(v, 8, 64);
            v += __shfl_xor(v, 16, 64);
            v += __shfl_xor(v, 32, 64);
            la[k] = v;
        }
        if (rl == 0) {                 // lanes 0..7 of each wave (lane == m)
            float4* wp = (float4*)&wpart[wave][m << 3];
            wp[0] = make_float4(la[0], la[1], la[2], la[3]);
            wp[1] = make_float4(la[4], la[5], la[6], la[7]);
        }
        __syncthreads();               // sync1: wpart ready

        // ---- Phase B: finalize 64 logits, exp (wave 0 only, now tiny) ----
        if (tid < 64) {
            const float l = wpart[0][tid] + wpart[1][tid]
                          + wpart[2][tid] + wpart[3][tid] + mb;
            const float e = expf(l);
            earr[tid] = e;
            zacc += e;                 // folded across chunks, reduced once
        }
        __syncthreads();               // sync2: earr ready; frees wpart

        // ---- Phase C: context accumulation from the register slice ----
        float el[8];
        #pragma unroll
        for (int j = 0; j < 8; ++j) el[j] = earr[(m << 3) + j];
        #pragma unroll
        for (int it = 0; it < 8; ++it) {
            acc[it] += d0[it].x * el[0] + d0[it].y * el[1]
                     + d0[it].z * el[2] + d0[it].w * el[3]
                     + d1[it].x * el[4] + d1[it].y * el[5]
                     + d1[it].z * el[6] + d1[it].w * el[7];
        }
        // no trailing barrier: next sync1 orders C's earr reads vs next-B's
        // earr writes; sync2 already ordered B's wpart reads vs next-A's
        // wpart writes.
    }

    // Fold the 8 n-octet lanes (m = low 3 lane bits): butterfly per it, then
    // lane m keeps channel c = m*32 + r. One atomic per (b,c) per block.
    float ctxv = 0.f;
    #pragma unroll
    for (int it = 0; it < 8; ++it) {
        float v = acc[it];
        v += __shfl_xor(v, 1, 64);
        v += __shfl_xor(v, 2, 64);
        v += __shfl_xor(v, 4, 64);
        if (m == it) ctxv = v;
    }
    atomicAdd(&ctxnum[(b << 8) + (m << 5) + r], ctxv);

    if (tid < 64) {
        float s = zacc;
        #pragma unroll
        for (int off = 32; off > 0; off >>= 1) s += __shfl_down(s, off, 64);
        if (tid == 0) atomicAdd(&zbuf[b], s);
    }
}

// ---------------------------------------------------------------------------
// Kernel 2: everything downstream of context (tiny). One block per batch.
//   ctx = num/Z -> cm1 matvec -> LayerNorm(C) -> ReLU -> cm2 -> sigmoid
//   -> out = ix @ out_w[:,:,2,2]^T + out_b ; att = sigmoid(ix @ att_w^T+att_b)
//   -> d_out = att * out   (fp32)
// ---------------------------------------------------------------------------
__global__ __launch_bounds__(256) void tail_kernel(
    const float* __restrict__ ctxnum, const float* __restrict__ zbuf,
    const float* __restrict__ cm1_w, const float* __restrict__ cm1_b,
    const float* __restrict__ ln_g,  const float* __restrict__ ln_b,
    const float* __restrict__ cm2_w, const float* __restrict__ cm2_b,
    const float* __restrict__ out_w, const float* __restrict__ out_b,
    const float* __restrict__ att_w, const float* __restrict__ att_b,
    float* __restrict__ outp)
{
    const int b = blockIdx.x, t = threadIdx.x;
    __shared__ float v[NCH];
    __shared__ float red[8];

    const float zinv = 1.f / zbuf[b];
    v[t] = ctxnum[(b << 8) + t] * zinv;
    __syncthreads();

    // cm1: h[t] = cm1_w[t,:] . ctx + cm1_b[t]
    float h = cm1_b[t];
    {
        const float4* wr = (const float4*)(cm1_w + ((size_t)t << 8));
        #pragma unroll
        for (int jj = 0; jj < 64; ++jj) {
            const float4 w = wr[jj];
            const int c = jj << 2;
            h += w.x * v[c] + w.y * v[c + 1] + w.z * v[c + 2] + w.w * v[c + 3];
        }
    }

    // LayerNorm over the 256 channels (across threads)
    float s1 = h, s2 = h * h;
    #pragma unroll
    for (int off = 32; off > 0; off >>= 1) {
        s1 += __shfl_down(s1, off, 64);
        s2 += __shfl_down(s2, off, 64);
    }
    if ((t & 63) == 0) { red[t >> 6] = s1; red[4 + (t >> 6)] = s2; }
    __syncthreads();
    const float mu  = (red[0] + red[1] + red[2] + red[3]) * (1.f / 256.f);
    const float ex2 = (red[4] + red[5] + red[6] + red[7]) * (1.f / 256.f);
    const float rs  = rsqrtf(ex2 - mu * mu + 1e-5f);
    float sv = (h - mu) * rs * ln_g[t] + ln_b[t];
    sv = fmaxf(sv, 0.f);
    __syncthreads();
    v[t] = sv;
    __syncthreads();

    // cm2 + sigmoid -> input_x
    float h2 = cm2_b[t];
    {
        const float4* wr = (const float4*)(cm2_w + ((size_t)t << 8));
        #pragma unroll
        for (int jj = 0; jj < 64; ++jj) {
            const float4 w = wr[jj];
            const int c = jj << 2;
            h2 += w.x * v[c] + w.y * v[c + 1] + w.z * v[c + 2] + w.w * v[c + 3];
        }
    }
    const float ix = 1.f / (1.f + expf(-h2));
    __syncthreads();
    v[t] = ix;
    __syncthreads();

    // output_conv: only the center tap of the 5x5 survives on 1x1 spatial
    float o = out_b[t];
    {
        const float* ow = out_w + (size_t)t * 6400 + 12;  // [t, c, 2, 2]
        #pragma unroll 8
        for (int c = 0; c < 256; ++c) o += ow[c * 25] * v[c];
    }

    // att gate
    float a = att_b[t];
    {
        const float4* wr = (const float4*)(att_w + ((size_t)t << 8));
        #pragma unroll
        for (int jj = 0; jj < 64; ++jj) {
            const float4 w = wr[jj];
            const int c = jj << 2;
            a += w.x * v[c] + w.y * v[c + 1] + w.z * v[c + 2] + w.w * v[c + 3];
        }
    }
    a = 1.f / (1.f + expf(-a));

    outp[(b << 8) + t] = a * o;
}

extern "C" void kernel_launch(void* const* d_in, const int* in_sizes, int n_in,
                              void* d_out, int out_size, void* d_ws, size_t ws_size,
                              hipStream_t stream) {
    (void)in_sizes; (void)n_in; (void)out_size; (void)ws_size;
    const float* x      = (const float*)d_in[0];
    const float* mask_w = (const float*)d_in[1];
    const float* mask_b = (const float*)d_in[2];
    const float* cm1_w  = (const float*)d_in[3];
    const float* cm1_b  = (const float*)d_in[4];
    const float* ln_g   = (const float*)d_in[5];
    const float* ln_b   = (const float*)d_in[6];
    const float* cm2_w  = (const float*)d_in[7];
    const float* cm2_b  = (const float*)d_in[8];
    const float* out_w  = (const float*)d_in[9];
    const float* out_b  = (const float*)d_in[10];
    const float* att_w  = (const float*)d_in[11];
    const float* att_b  = (const float*)d_in[12];

    float* zbuf   = (float*)d_ws;          // 32 floats
    float* ctxnum = zbuf + 32;             // 32*256 floats

    hipMemsetAsync(d_ws, 0, (32 + BATCH * NCH) * sizeof(float), stream);

    spool_kernel<<<BATCH * 64, 256, 0, stream>>>(x, mask_w, mask_b, ctxnum, zbuf);

    tail_kernel<<<BATCH, 256, 0, stream>>>(ctxnum, zbuf,
                                           cm1_w, cm1_b, ln_g, ln_b,
                                           cm2_w, cm2_b, out_w, out_b,
                                           att_w, att_b, (float*)d_out);
}

// Round 4
// 792.676 us; speedup vs baseline: 1.1610x; 1.1610x over previous
//
#include <hip/hip_runtime.h>

typedef unsigned int uint;

#define BATCH 32
#define NCH   256
#define HW    16384

// ---------------------------------------------------------------------------
// Kernel 1: fused spatial pool, single pass over x (512 MiB fp32).
// e_n = exp(<x[:,n],w>+b) accumulated UNNORMALIZED (|logit| <~ 4, exp safe in
// fp32): ctxnum[b,c] = sum_n x[b,c,n]*e_n, zbuf[b] = sum_n e_n via fp32
// atomics; the division happens in the tail kernel.
//
// v3: WAVE-AUTONOMOUS main loop — zero __syncthreads in the chunk loop.
// Each wave owns 16 n-columns (per chunk) and ALL 256 channels for them:
//   lane l: rows c = 16*i + (l>>2), i=0..15; n-quad q = l&3 (4 floats).
// Logit(n) finalizes with an in-wave butterfly over lane bits 2..5
// (shfl_xor 4/8/16/32); exp in-register; context FMAs reuse the same d[16]
// registers. Waves never convoy at block barriers; cross-wave combine is a
// single LDS partial + 1 barrier at kernel end.
//
// Lessons encoded:
//  * NO __launch_bounds__ min-waves: round-2's (256,4) capped VGPR at 128 and
//    forced scratch spills in the loop (~+130 us). Live regs here ~115; let
//    the allocator breathe.
//  * x touched exactly once; no LDS data tile; 5 KB LDS total.
// ---------------------------------------------------------------------------
__global__ __launch_bounds__(256) void spool_kernel(
    const float* __restrict__ x, const float* __restrict__ mask_w,
    const float* __restrict__ mask_b, float* __restrict__ ctxnum,
    float* __restrict__ zbuf)
{
    __shared__ float wlds[NCH];
    __shared__ float wpart[4][NCH];   // per-wave ctx partials
    __shared__ float zarr[4];

    const int tid  = threadIdx.x;
    const int b    = blockIdx.x >> 6;
    const int blk  = blockIdx.x & 63;
    const int wave = tid >> 6;        // 0..3: 16-n window within the chunk
    const int l    = tid & 63;
    const int q    = l & 3;           // n-quad (4 consecutive n)
    const int rr   = l >> 2;          // row offset 0..15

    wlds[tid] = mask_w[tid];
    const float mb = mask_b[0];
    __syncthreads();

    // This lane's 16 channel weights: c = 16*i + rr.
    float wcr[16];
    #pragma unroll
    for (int i = 0; i < 16; ++i) wcr[i] = wlds[(i << 4) + rr];

    float acc[16];
    #pragma unroll
    for (int i = 0; i < 16; ++i) acc[i] = 0.f;
    float zacc = 0.f;                 // each n's e counted 16x (all lanes)

    // Lane base: row rr, n-offset wave*16 + q*4 inside the block's window.
    const float* xb = x + ((size_t)b << 22) + ((size_t)rr << 14)
                        + (wave << 4) + (q << 2);

    for (int g = 0; g < 4; ++g) {
        const int n0 = (blk << 8) + (g << 6);

        // ---- load 16 rows (float4 each) + logit partials ----
        float4 d[16];
        float la[4] = {0.f, 0.f, 0.f, 0.f};
        #pragma unroll
        for (int i = 0; i < 16; ++i) {
            d[i] = *(const float4*)(xb + ((size_t)i << 18) + n0); // rows 16 apart
            const float w = wcr[i];
            la[0] += w * d[i].x; la[1] += w * d[i].y;
            la[2] += w * d[i].z; la[3] += w * d[i].w;
        }

        // ---- in-wave butterfly over the 16 row-lanes (bits 2..5) ----
        #pragma unroll
        for (int k = 0; k < 4; ++k) {
            float v = la[k];
            v += __shfl_xor(v, 4, 64);
            v += __shfl_xor(v, 8, 64);
            v += __shfl_xor(v, 16, 64);
            v += __shfl_xor(v, 32, 64);
            la[k] = v;
        }

        // ---- exp + Z partial + context accumulation (no barriers) ----
        float e[4];
        #pragma unroll
        for (int k = 0; k < 4; ++k) e[k] = expf(la[k] + mb);
        zacc += e[0] + e[1] + e[2] + e[3];
        #pragma unroll
        for (int i = 0; i < 16; ++i) {
            acc[i] += d[i].x * e[0] + d[i].y * e[1]
                    + d[i].z * e[2] + d[i].w * e[3];
        }
    }

    // Fold each row across the 4 n-quad lanes (bits 0..1).
    #pragma unroll
    for (int i = 0; i < 16; ++i) {
        float v = acc[i];
        v += __shfl_xor(v, 1, 64);
        v += __shfl_xor(v, 2, 64);
        acc[i] = v;
    }
    // Lanes q==0 (16 of them) publish their 16 complete row sums.
    if (q == 0) {
        #pragma unroll
        for (int i = 0; i < 16; ++i) wpart[wave][(i << 4) + rr] = acc[i];
    }
    // Z: wave-reduce (each e replicated 16x across lanes -> scale by 1/16).
    {
        float s = zacc;
        #pragma unroll
        for (int off = 32; off > 0; off >>= 1) s += __shfl_down(s, off, 64);
        if (l == 0) zarr[wave] = s * (1.f / 16.f);
    }
    __syncthreads();

    // Cross-wave combine: thread t owns channel t. One atomic per (b,c).
    const float ctxv = wpart[0][tid] + wpart[1][tid]
                     + wpart[2][tid] + wpart[3][tid];
    atomicAdd(&ctxnum[(b << 8) + tid], ctxv);
    if (tid == 0) atomicAdd(&zbuf[b], zarr[0] + zarr[1] + zarr[2] + zarr[3]);
}

// ---------------------------------------------------------------------------
// Kernel 2: everything downstream of context (tiny). One block per batch.
//   ctx = num/Z -> cm1 matvec -> LayerNorm(C) -> ReLU -> cm2 -> sigmoid
//   -> out = ix @ out_w[:,:,2,2]^T + out_b ; att = sigmoid(ix @ att_w^T+att_b)
//   -> d_out = att * out   (fp32)
// ---------------------------------------------------------------------------
__global__ __launch_bounds__(256) void tail_kernel(
    const float* __restrict__ ctxnum, const float* __restrict__ zbuf,
    const float* __restrict__ cm1_w, const float* __restrict__ cm1_b,
    const float* __restrict__ ln_g,  const float* __restrict__ ln_b,
    const float* __restrict__ cm2_w, const float* __restrict__ cm2_b,
    const float* __restrict__ out_w, const float* __restrict__ out_b,
    const float* __restrict__ att_w, const float* __restrict__ att_b,
    float* __restrict__ outp)
{
    const int b = blockIdx.x, t = threadIdx.x;
    __shared__ float v[NCH];
    __shared__ float red[8];

    const float zinv = 1.f / zbuf[b];
    v[t] = ctxnum[(b << 8) + t] * zinv;
    __syncthreads();

    // cm1: h[t] = cm1_w[t,:] . ctx + cm1_b[t]
    float h = cm1_b[t];
    {
        const float4* wr = (const float4*)(cm1_w + ((size_t)t << 8));
        #pragma unroll
        for (int jj = 0; jj < 64; ++jj) {
            const float4 w = wr[jj];
            const int c = jj << 2;
            h += w.x * v[c] + w.y * v[c + 1] + w.z * v[c + 2] + w.w * v[c + 3];
        }
    }

    // LayerNorm over the 256 channels (across threads)
    float s1 = h, s2 = h * h;
    #pragma unroll
    for (int off = 32; off > 0; off >>= 1) {
        s1 += __shfl_down(s1, off, 64);
        s2 += __shfl_down(s2, off, 64);
    }
    if ((t & 63) == 0) { red[t >> 6] = s1; red[4 + (t >> 6)] = s2; }
    __syncthreads();
    const float mu  = (red[0] + red[1] + red[2] + red[3]) * (1.f / 256.f);
    const float ex2 = (red[4] + red[5] + red[6] + red[7]) * (1.f / 256.f);
    const float rs  = rsqrtf(ex2 - mu * mu + 1e-5f);
    float sv = (h - mu) * rs * ln_g[t] + ln_b[t];
    sv = fmaxf(sv, 0.f);
    __syncthreads();
    v[t] = sv;
    __syncthreads();

    // cm2 + sigmoid -> input_x
    float h2 = cm2_b[t];
    {
        const float4* wr = (const float4*)(cm2_w + ((size_t)t << 8));
        #pragma unroll
        for (int jj = 0; jj < 64; ++jj) {
            const float4 w = wr[jj];
            const int c = jj << 2;
            h2 += w.x * v[c] + w.y * v[c + 1] + w.z * v[c + 2] + w.w * v[c + 3];
        }
    }
    const float ix = 1.f / (1.f + expf(-h2));
    __syncthreads();
    v[t] = ix;
    __syncthreads();

    // output_conv: only the center tap of the 5x5 survives on 1x1 spatial
    float o = out_b[t];
    {
        const float* ow = out_w + (size_t)t * 6400 + 12;  // [t, c, 2, 2]
        #pragma unroll 8
        for (int c = 0; c < 256; ++c) o += ow[c * 25] * v[c];
    }

    // att gate
    float a = att_b[t];
    {
        const float4* wr = (const float4*)(att_w + ((size_t)t << 8));
        #pragma unroll
        for (int jj = 0; jj < 64; ++jj) {
            const float4 w = wr[jj];
            const int c = jj << 2;
            a += w.x * v[c] + w.y * v[c + 1] + w.z * v[c + 2] + w.w * v[c + 3];
        }
    }
    a = 1.f / (1.f + expf(-a));

    outp[(b << 8) + t] = a * o;
}

extern "C" void kernel_launch(void* const* d_in, const int* in_sizes, int n_in,
                              void* d_out, int out_size, void* d_ws, size_t ws_size,
                              hipStream_t stream) {
    (void)in_sizes; (void)n_in; (void)out_size; (void)ws_size;
    const float* x      = (const float*)d_in[0];
    const float* mask_w = (const float*)d_in[1];
    const float* mask_b = (const float*)d_in[2];
    const float* cm1_w  = (const float*)d_in[3];
    const float* cm1_b  = (const float*)d_in[4];
    const float* ln_g   = (const float*)d_in[5];
    const float* ln_b   = (const float*)d_in[6];
    const float* cm2_w  = (const float*)d_in[7];
    const float* cm2_b  = (const float*)d_in[8];
    const float* out_w  = (const float*)d_in[9];
    const float* out_b  = (const float*)d_in[10];
    const float* att_w  = (const float*)d_in[11];
    const float* att_b  = (const float*)d_in[12];

    float* zbuf   = (float*)d_ws;          // 32 floats
    float* ctxnum = zbuf + 32;             // 32*256 floats

    hipMemsetAsync(d_ws, 0, (32 + BATCH * NCH) * sizeof(float), stream);

    spool_kernel<<<BATCH * 64, 256, 0, stream>>>(x, mask_w, mask_b, ctxnum, zbuf);

    tail_kernel<<<BATCH, 256, 0, stream>>>(ctxnum, zbuf,
                                           cm1_w, cm1_b, ln_g, ln_b,
                                           cm2_w, cm2_b, out_w, out_b,
                                           att_w, att_b, (float*)d_out);
}